// Round 7
// baseline (264.173 us; speedup 1.0000x reference)
//
#include <hip/hip_runtime.h>
#include <math.h>

namespace {
constexpr int kB = 4096, kN = 128, kT = 20, kD = 64, kP = 8;
constexpr float kTwoPi = 6.28318530717958647692f;
constexpr float kBinW  = 0.78539816339744830962f;  // 2pi/8 in f32
}

// One block per batch element. Phases:
//  (0) issue 8 float4 f_resonance loads -> registers (T14 prefetch, pinned)
//  (1) coalesced nei sweep -> LDS per-float4 partial sums + last-frame xy
//  (2) 128 lanes: mask sum, dist/dir/bin, 8-wide scan atomics
//  (3) select-FMA consume of prefetched resonance regs, wave reduce
//  (4) coalesced epilogue (resonance/n | relu(scan @ W + b))
__global__ __launch_bounds__(256)
void circle_fused(const float* __restrict__ ego,
                  const float* __restrict__ nei,
                  const float* __restrict__ fres,
                  const float* __restrict__ Wce,
                  const float* __restrict__ bce,
                  float* __restrict__ out) {
  const int b = blockIdx.x, tid = threadIdx.x;
  const int lane = tid & 63, wv = tid >> 6;
  const int rsub = lane >> 4;            // row subgroup (4 rows per iter)
  const int dq   = lane & 15;            // float4 index within a row

  __shared__ float  s_psum[kN * 10];     // per-float4 partial sums (5 KB)
  __shared__ float  s_last[kN * 2];      // last-frame x,y per neighbor (1 KB)
  __shared__ int    s_bin[kN];
  __shared__ float  s_cnt[kP], s_d[kP], s_th[kP];
  __shared__ float4 s_res[4][kP][kD / 4];  // 8 KB wave partials

  if (tid < kP) { s_cnt[tid] = 0.f; s_d[tid] = 0.f; s_th[tid] = 0.f; }

  // ---- phase 0: prefetch resonance (32 KB/block) into registers
  const float4* r4 = reinterpret_cast<const float4*>(fres + (size_t)b * (kN * kD));
  float4 rv[8];
  #pragma unroll
  for (int k = 0; k < 8; ++k) {
    const int n = wv * 32 + k * 4 + rsub;
    rv[k] = r4[n * 16 + dq];             // 1 KB contiguous per wave instr
  }

  // ---- phase 1: nei sweep (20 KB/block), perfectly coalesced, no atomics
  const float4* nb4 = reinterpret_cast<const float4*>(nei + (size_t)b * (kN * kT * 2));
  #pragma unroll
  for (int i = 0; i < 5; ++i) {
    const int j = tid + 256 * i;         // 0..1279
    const float4 v = nb4[j];
    s_psum[j] = (v.x + v.y) + (v.z + v.w);
    const int n = j / 10;                // 10 float4 per neighbor
    if (j - n * 10 == 9) { s_last[2 * n] = v.z; s_last[2 * n + 1] = v.w; }
  }
  // pin the prefetched values live here so the loads cannot sink below the
  // barrier (rule #17 keep-alive; zero-cost)
  #pragma unroll
  for (int k = 0; k < 8; ++k)
    asm volatile("" : "+v"(rv[k].x), "+v"(rv[k].y), "+v"(rv[k].z), "+v"(rv[k].w));
  __syncthreads();

  // ---- phase 2: per-neighbor bin (128 lanes; psum stride 10 words = 2-way, free)
  if (tid < kN) {
    float tot = 0.f;
    #pragma unroll
    for (int k = 0; k < 10; ++k) tot += s_psum[tid * 10 + k];
    const float egx = ego[(size_t)b * (kT * 2) + 38];
    const float egy = ego[(size_t)b * (kT * 2) + 39];
    const float rx = s_last[2 * tid] - egx;
    const float ry = s_last[2 * tid + 1] - egy;
    const float dist = sqrtf(rx * rx + ry * ry);
    // correctly-rounded f32 atan2 via double (bit-matches numpy; proven R4/R5)
    float dir = (float)atan2((double)rx, (double)ry);
    if (dir < 0.0f) dir += kTwoPi;
    int idx = (int)(dir / kBinW);        // trunc, matches astype(int32)
    if (tot == 0.0f) idx = -1;           // invalid neighbor -> -1
    s_bin[tid] = idx;                    // idx==8 possible; dropped below
    if (idx >= 0 && idx < kP) {          // 128 lanes -> 8 addrs, negligible
      atomicAdd(&s_cnt[idx], 1.0f);
      atomicAdd(&s_d[idx],  dist);
      atomicAdd(&s_th[idx], dir);
    }
  }
  __syncthreads();

  // ---- phase 3: select-FMA over the prefetched registers
  float acc[kP][4];
  #pragma unroll
  for (int p = 0; p < kP; ++p) { acc[p][0] = acc[p][1] = acc[p][2] = acc[p][3] = 0.f; }
  #pragma unroll
  for (int k = 0; k < 8; ++k) {
    const int n = wv * 32 + k * 4 + rsub;
    const int bin = s_bin[n];
    const float4 v = rv[k];
    #pragma unroll
    for (int p = 0; p < kP; ++p) {
      const float mf = (bin == p) ? 1.0f : 0.0f;
      acc[p][0] = fmaf(v.x, mf, acc[p][0]);
      acc[p][1] = fmaf(v.y, mf, acc[p][1]);
      acc[p][2] = fmaf(v.z, mf, acc[p][2]);
      acc[p][3] = fmaf(v.w, mf, acc[p][3]);
    }
  }
  #pragma unroll
  for (int p = 0; p < kP; ++p) {
    #pragma unroll
    for (int j = 0; j < 4; ++j) {
      float x = acc[p][j];
      x += __shfl_xor(x, 16, 64);
      x += __shfl_xor(x, 32, 64);
      acc[p][j] = x;
    }
  }
  if (lane < 16) {
    #pragma unroll
    for (int p = 0; p < kP; ++p)
      s_res[wv][p][dq] = make_float4(acc[p][0], acc[p][1], acc[p][2], acc[p][3]);
  }
  __syncthreads();

  // ---- phase 4: epilogue, 256 float4 coalesced stores
  const int p = tid >> 5, q = tid & 31;
  const float nf = s_cnt[p] + 1e-4f;
  float* ob = out + (size_t)b * (kP * 2 * kD) + p * (2 * kD);
  if (q < 16) {                          // resonance_circle half
    const float4 a = s_res[0][p][q], c = s_res[1][p][q];
    const float4 d2 = s_res[2][p][q], e = s_res[3][p][q];
    float4 o;
    o.x = (a.x + c.x + d2.x + e.x) / nf;
    o.y = (a.y + c.y + d2.y + e.y) / nf;
    o.z = (a.z + c.z + d2.z + e.z) / nf;
    o.w = (a.w + c.w + d2.w + e.w) / nf;
    reinterpret_cast<float4*>(ob)[q] = o;
  } else {                               // f_scan: relu(s0*W0 + s1*W1 + b)
    const int d = (q - 16) * 4;
    const float s0 = s_d[p] / nf;
    const float s1 = s_th[p] / nf;
    float4 o;
    o.x = fmaxf(s0 * Wce[d + 0] + s1 * Wce[kD + d + 0] + bce[d + 0], 0.0f);
    o.y = fmaxf(s0 * Wce[d + 1] + s1 * Wce[kD + d + 1] + bce[d + 1], 0.0f);
    o.z = fmaxf(s0 * Wce[d + 2] + s1 * Wce[kD + d + 2] + bce[d + 2], 0.0f);
    o.w = fmaxf(s0 * Wce[d + 3] + s1 * Wce[kD + d + 3] + bce[d + 3], 0.0f);
    reinterpret_cast<float4*>(ob + kD)[q - 16] = o;
  }
}

extern "C" void kernel_launch(void* const* d_in, const int* in_sizes, int n_in,
                              void* d_out, int out_size, void* d_ws, size_t ws_size,
                              hipStream_t stream) {
  const float* ego  = (const float*)d_in[0];
  const float* nei  = (const float*)d_in[1];
  const float* fres = (const float*)d_in[2];
  const float* Wce  = (const float*)d_in[3];
  const float* bce  = (const float*)d_in[4];
  float* out = (float*)d_out;
  hipLaunchKernelGGL(circle_fused, dim3(kB), dim3(256), 0, stream,
                     ego, nei, fres, Wce, bce, out);
}